// Round 1
// baseline (48188.779 us; speedup 1.0000x reference)
//
#include <hip/hip_runtime.h>

// GRU  B=128, T=1024, IN=256, H=512, OUT=1  (all fp32)
//
// Design: persistent cooperative kernel, 256 wgs x 256 thr (1 wg/CU via LDS pad).
//   8 groups (one per XCD via blockIdx%8) x 32 wgs. Group owns 16 samples.
//   wg owns 16 hidden indices j -> 48 rows of W_hh AND W_ih, kept in REGISTERS
//   (thread (j,ks): W_hh[3][j][32ks..32ks+32) = 96 regs, W_ih[3][j][16ks..+16) = 48).
//   Per step: dot-products from registers x (global h/x reads, L1-cached),
//   16-lane shfl_xor reduce, gates, h exchanged via global double buffer +
//   per-group monotonic atomic barrier (release/acquire, agent scope).
//   Global h read offsets XOR-permuted per-thread; the permutation is absorbed
//   into the weight-register load order so the inner loop has constant offsets.

#define B_   128
#define T_   1024
#define IN_  256
#define H_   512
#define NG   8
#define WPG  32
#define SG   16
#define JT   16
#define DYN_LDS (84*1024)   // forces 1 wg/CU (2x84KB > 160KB)

__device__ __forceinline__ float sig_(float v){ return 1.0f/(1.0f + __expf(-v)); }
__device__ __forceinline__ float tanh_(float v){
  float e = __expf(2.0f*v);            // tanh = 1 - 2/(e^{2x}+1); inf-safe
  return 1.0f - 2.0f/(e + 1.0f);
}

#define FMA4(acc, v, warr, base) do{            \
  acc = fmaf((v).x, warr[(base)+0], acc);       \
  acc = fmaf((v).y, warr[(base)+1], acc);       \
  acc = fmaf((v).z, warr[(base)+2], acc);       \
  acc = fmaf((v).w, warr[(base)+3], acc); }while(0)

__global__ void __launch_bounds__(256, 1)
rnn_persist(const float* __restrict__ x, const float* __restrict__ W_ih,
            const float* __restrict__ W_hh, const float* __restrict__ bias,
            const float* __restrict__ bias_n, float* __restrict__ h_buf,
            int* __restrict__ counters)
{
  const int bid   = (int)blockIdx.x;
  const int g     = bid & (NG-1);      // group -> XCD heuristic
  const int w     = bid >> 3;          // wg within group [0,32)
  const int tid   = (int)threadIdx.x;
  const int j_loc = tid >> 4;          // [0,16)
  const int ks    = tid & 15;          // k-chunk [0,16)
  const int jg    = w*JT + j_loc;      // global hidden index [0,512)
  const int b0    = g*SG;              // first sample of group
  const int krow  = ks*32;             // h k-chunk start
  const int kxrow = ks*16;             // x k-chunk start
  const int swz   = (4*ks) & 31;       // bank-rotation XOR (multiple of 4)

  __shared__ float hnew_sh[SG][JT];

  // ---- weights into registers (phys slot i <-> logical offset (4i)^swz) ----
  float wr[32], wz[32], wn[32];
#pragma unroll
  for (int i=0;i<8;i++){
    const int kk = krow + ((4*i)^swz);
    const float4 a  = *(const float4*)&W_hh[(size_t)(      jg)*H_ + kk];
    const float4 b4 = *(const float4*)&W_hh[(size_t)(H_  + jg)*H_ + kk];
    const float4 c  = *(const float4*)&W_hh[(size_t)(2*H_+ jg)*H_ + kk];
    wr[4*i+0]=a.x;  wr[4*i+1]=a.y;  wr[4*i+2]=a.z;  wr[4*i+3]=a.w;
    wz[4*i+0]=b4.x; wz[4*i+1]=b4.y; wz[4*i+2]=b4.z; wz[4*i+3]=b4.w;
    wn[4*i+0]=c.x;  wn[4*i+1]=c.y;  wn[4*i+2]=c.z;  wn[4*i+3]=c.w;
  }
  float wxr[16], wxz[16], wxn[16];
#pragma unroll
  for (int i=0;i<4;i++){
    const int kk = kxrow + 4*i;
    const float4 a  = *(const float4*)&W_ih[(size_t)(      jg)*IN_ + kk];
    const float4 b4 = *(const float4*)&W_ih[(size_t)(H_  + jg)*IN_ + kk];
    const float4 c  = *(const float4*)&W_ih[(size_t)(2*H_+ jg)*IN_ + kk];
    wxr[4*i+0]=a.x;  wxr[4*i+1]=a.y;  wxr[4*i+2]=a.z;  wxr[4*i+3]=a.w;
    wxz[4*i+0]=b4.x; wxz[4*i+1]=b4.y; wxz[4*i+2]=b4.z; wxz[4*i+3]=b4.w;
    wxn[4*i+0]=c.x;  wxn[4*i+1]=c.y;  wxn[4*i+2]=c.z;  wxn[4*i+3]=c.w;
  }
  const float br  = bias[jg];
  const float bz  = bias[H_ + jg];
  const float bni = bias[2*H_ + jg];
  const float bnh = bias_n[jg];

  float* const hb0 = h_buf;
  float* const hb1 = h_buf + (size_t)B_*H_;
  int dead = 0;

  for (int t=0; t<T_; ++t){
    const float* hc  = (t & 1) ? hb1 : hb0;
    float*       hnx = (t & 1) ? hb0 : hb1;

#pragma unroll 2
    for (int bb=0; bb<SG; ++bb){
      const float* hrowp = hc + (size_t)(b0+bb)*H_ + krow;
      const float* xrowp = x  + ((size_t)(b0+bb)*T_ + (size_t)t)*IN_ + kxrow;
      float accr=0.f, accz=0.f, accnh=0.f, accni=0.f;
#pragma unroll
      for (int i=0;i<8;i++){
        const float4 h4 = *(const float4*)(hrowp + ((4*i)^swz));
        FMA4(accr, h4, wr, 4*i);
        FMA4(accz, h4, wz, 4*i);
        FMA4(accnh,h4, wn, 4*i);
      }
#pragma unroll
      for (int i=0;i<4;i++){
        const float4 x4 = *(const float4*)(xrowp + 4*i);
        FMA4(accr, x4, wxr, 4*i);
        FMA4(accz, x4, wxz, 4*i);
        FMA4(accni,x4, wxn, 4*i);
      }
      // reduce partial sums across the 16 ks-lanes (result in all lanes)
#pragma unroll
      for (int m=1;m<16;m<<=1){
        accr  += __shfl_xor(accr,  m, 16);
        accz  += __shfl_xor(accz,  m, 16);
        accnh += __shfl_xor(accnh, m, 16);
        accni += __shfl_xor(accni, m, 16);
      }
      const float h_old = hc[(size_t)(b0+bb)*H_ + jg];
      const float r = sig_(accr + br);
      const float z = sig_(accz + bz);
      const float n = tanh_(accni + bni + r*(accnh + bnh));
      const float hnew = (1.0f - z)*n + z*h_old;
      if (ks == 0) hnew_sh[bb][j_loc] = hnew;
    }
    __syncthreads();
    // coalesced write of this wg's j-slice for all 16 samples
    hnx[(size_t)(b0 + (tid>>4))*H_ + w*JT + (tid & 15)] = hnew_sh[tid>>4][tid&15];
    __threadfence();
    __syncthreads();
    // per-group barrier: monotonic counter, no reset needed within a launch
    if (tid == 0 && !dead){
      __hip_atomic_fetch_add(&counters[g*64], 1, __ATOMIC_RELEASE, __HIP_MEMORY_SCOPE_AGENT);
      const int target = WPG*(t+1);
      long long guard = 0;
      while (__hip_atomic_load(&counters[g*64], __ATOMIC_ACQUIRE, __HIP_MEMORY_SCOPE_AGENT) < target){
        __builtin_amdgcn_s_sleep(2);
        if (++guard > (1LL<<18)) { dead = 1; break; }  // anti-hang bailout
      }
    }
    __syncthreads();
  }
}

__global__ void head_k(const float* __restrict__ h, const float* __restrict__ W_out,
                       const float* __restrict__ b_out, float* __restrict__ out)
{
  const int b = (int)threadIdx.x;
  if (b < B_){
    float acc = 0.f;
    for (int k=0;k<H_;k++) acc = fmaf(h[(size_t)b*H_ + k], W_out[k], acc);
    out[b] = sig_(acc + b_out[0]);
  }
}

extern "C" void kernel_launch(void* const* d_in, const int* in_sizes, int n_in,
                              void* d_out, int out_size, void* d_ws, size_t ws_size,
                              hipStream_t stream)
{
  const float* x    = (const float*)d_in[0];
  const float* Wih  = (const float*)d_in[1];
  const float* Whh  = (const float*)d_in[2];
  const float* bias = (const float*)d_in[3];
  const float* bn   = (const float*)d_in[4];
  const float* Wout = (const float*)d_in[5];
  const float* bout = (const float*)d_in[6];
  float* out   = (float*)d_out;
  float* h_buf = (float*)d_ws;                                   // 2*128*512 f32 = 512KB
  int* counters = (int*)((char*)d_ws + (size_t)2*B_*H_*sizeof(float)); // 8 x 256B stride

  // zero h0 + barrier counters every launch (captured into the graph)
  hipMemsetAsync(d_ws, 0, (size_t)2*B_*H_*sizeof(float) + 4096, stream);
  (void)hipFuncSetAttribute((const void*)rnn_persist,
                            hipFuncAttributeMaxDynamicSharedMemorySize, DYN_LDS);

  void* args[7];
  args[0]=(void*)&x; args[1]=(void*)&Wih; args[2]=(void*)&Whh; args[3]=(void*)&bias;
  args[4]=(void*)&bn; args[5]=(void*)&h_buf; args[6]=(void*)&counters;
  hipError_t e = hipLaunchCooperativeKernel((const void*)rnn_persist,
                                            dim3(256), dim3(256), args, DYN_LDS, stream);
  if (e != hipSuccess){
    (void)hipGetLastError();
    rnn_persist<<<dim3(256), dim3(256), DYN_LDS, stream>>>(x, Wih, Whh, bias, bn, h_buf, counters);
    if (hipGetLastError() != hipSuccess){
      // last resort: no LDS pad (blocks may pack 2/CU but all stay resident)
      rnn_persist<<<dim3(256), dim3(256), 0, stream>>>(x, Wih, Whh, bias, bn, h_buf, counters);
    }
  }
  head_k<<<dim3(1), dim3(128), 0, stream>>>(h_buf, Wout, bout, out);
}